// Round 7
// baseline (166.965 us; speedup 1.0000x reference)
//
#include <hip/hip_runtime.h>

// GraphConv B=256,N=512,D=6,F=128,MAX_DEG=6.
// R6 post-mortem: k1 45us (LDS gather works, FETCH 99->39MB) but 2 blocks/CU
// (76KB LDS) -> phase-serial, latency-exposed. k2 ~40us, epilogue = 64 scalar
// 4B stores/lane (~27us store issue). R7:
//   k1: 8 slices x 16 cols -> 43KB LDS, 3 blocks/CU, 2048 blocks.
//   k2: swapped-operand MFMA (D = [outcol][atom]) -> 16 float4 stores/lane.

typedef short bf16x8 __attribute__((ext_vector_type(8)));
typedef float f32x4  __attribute__((ext_vector_type(4)));
typedef unsigned short ushort_t;
typedef unsigned int uint_t;

constexpr int Nn = 512;
constexpr int Ff = 128;
constexpr int BN = 256 * 512;             // 131072 atoms
constexpr int RS = 18;                    // LDS row stride: 16 floats + 2 pad

// ws layout (bytes)
constexpr size_t WS_GC     = 0;                         // i32 [6] (+pad to 256)
constexpr size_t WS_REGION = 256;                       // i32 [6][BN]
constexpr size_t WS_WT     = 256 + (size_t)6 * BN * 4;  // bf16 [6][128][128]
constexpr size_t WS_SUMMED = WS_WT + 196608;            // bf16 [BN][128]
constexpr size_t WS_NEEDED = WS_SUMMED + (size_t)BN * 128 * 2;   // ~36.9 MB

__device__ inline ushort_t f2bf(float f) {              // round-to-nearest-even
    uint_t u = __float_as_uint(f);
    return (ushort_t)((u + 0x7FFFu + ((u >> 16) & 1u)) >> 16);
}

__device__ inline bool detect_is64(const int* edges32) {
    // int64 edges: odd dwords are sign-extension words in {0,-1}.
    int probe = edges32[2 * (threadIdx.x & 63) + 1];
    return __any(probe > 0) == 0;
}

// ---------------- K1: molecule-resident LDS gather ----------------
// grid: 2048 blocks = 256 molecules x 8 column-slices of 16 floats.
__global__ __launch_bounds__(256, 3)
void k1_pre(const float* __restrict__ atoms,
            const int*   __restrict__ edges32,
            const float* __restrict__ W,
            int* __restrict__ gcnt,
            int* __restrict__ region,
            ushort_t* __restrict__ Wt,
            ushort_t* __restrict__ summed) {
    const int tid   = threadIdx.x;
    const int mol   = blockIdx.x >> 3;
    const int slice = blockIdx.x & 7;
    const bool is64 = detect_is64(edges32);   // convergent

    __shared__ float    Arows[Nn * RS];          // 36864 B
    __shared__ ushort_t nbp[Nn * 6];             // 6144 B (packed nbr ids)
    __shared__ int      hist[6], base_sh[6];

    // W -> bf16 transposed [d][n][k]: first 384 blocks, 256 elts each
    if (blockIdx.x < 384) {
        int linear = blockIdx.x * 256 + tid;          // [d][k][n] linear, 98304
        int d = linear >> 14, rem = linear & 16383;
        int k = rem >> 7, n = rem & 127;
        Wt[d * 16384 + n * 128 + k] = f2bf(W[linear]);
    }

    // ---- stage edges (packed u16; 0xFFFF = invalid) ----
    {
        const size_t ebase = (size_t)mol * (Nn * 6);
        #pragma unroll
        for (int it = 0; it < 12; it++) {
            int i = tid + it * 256;
            int e = is64 ? edges32[(ebase + i) * 2] : edges32[ebase + i];
            nbp[i] = (ushort_t)(e >= 0 ? e : 0xFFFF);
        }
    }

    // ---- stage atom slice: 512 rows x 16 floats, coalesced ----
    {
        const float4* gsrc = (const float4*)(atoms + (size_t)mol * (Nn * Ff) + slice * 16);
        #pragma unroll
        for (int it = 0; it < 8; it++) {
            int idx = tid + it * 256;         // float4 index in slice (2048)
            int row = idx >> 2, q = idx & 3;
            float4 v = gsrc[row * 32 + q];    // row stride 128 floats = 32 float4
            int la = row * RS + q * 4;
            float2 p0; p0.x = v.x; p0.y = v.y;
            float2 p1; p1.x = v.z; p1.y = v.w;
            *(float2*)&Arows[la]     = p0;    // 8B-aligned (la even)
            *(float2*)&Arows[la + 2] = p1;
        }
    }
    __syncthreads();

    // ---- slice 0: degree-scatter via LDS-atomic ranks ----
    if (slice == 0) {
        if (tid < 6) hist[tid] = 0;
        __syncthreads();
        int dg[2], rk[2];
        #pragma unroll
        for (int s = 0; s < 2; s++) {
            int row = tid + s * 256;
            int dd = 0;
            #pragma unroll
            for (int j = 0; j < 6; j++) dd += (nbp[row * 6 + j] != 0xFFFF) ? 1 : 0;
            dg[s] = dd;
            rk[s] = atomicAdd(&hist[dd], 1);
        }
        __syncthreads();
        if (tid < 6) base_sh[tid] = atomicAdd(&gcnt[tid], hist[tid]);
        __syncthreads();
        #pragma unroll
        for (int s = 0; s < 2; s++)
            region[dg[s] * BN + base_sh[dg[s]] + rk[s]] = mol * Nn + tid + s * 256;
    }

    // ---- gather-sum from LDS: 2 threads/row x 8 floats, 4 rounds ----
    const int h = tid & 1, cbase = h * 8;
    #pragma unroll
    for (int rd = 0; rd < 4; rd++) {
        const int row = rd * 128 + (tid >> 1);
        float2 acc[4];
        #pragma unroll
        for (int c = 0; c < 4; c++)
            acc[c] = *(const float2*)&Arows[row * RS + cbase + 2 * c];
        #pragma unroll
        for (int j = 0; j < 6; j++) {
            int e = nbp[row * 6 + j];
            if (e != 0xFFFF) {
                const float* src = &Arows[e * RS + cbase];
                #pragma unroll
                for (int c = 0; c < 4; c++) {
                    float2 v = *(const float2*)&src[2 * c];
                    acc[c].x += v.x; acc[c].y += v.y;
                }
            }
        }
        uint4 o;
        o.x = (uint_t)f2bf(acc[0].x) | ((uint_t)f2bf(acc[0].y) << 16);
        o.y = (uint_t)f2bf(acc[1].x) | ((uint_t)f2bf(acc[1].y) << 16);
        o.z = (uint_t)f2bf(acc[2].x) | ((uint_t)f2bf(acc[2].y) << 16);
        o.w = (uint_t)f2bf(acc[3].x) | ((uint_t)f2bf(acc[3].y) << 16);
        *(uint4*)(summed + (size_t)(mol * Nn + row) * Ff + slice * 16 + cbase) = o;
    }
}

// ---------------- K2: GEMM, swapped operands (D = [outcol][atom]) ----------------
__global__ __launch_bounds__(256, 4)
void k2_gemm(const ushort_t* __restrict__ summed,
             const float*    __restrict__ bias,
             const ushort_t* __restrict__ Wt,
             const int*      __restrict__ region,
             const int*      __restrict__ gcnt,
             float*          __restrict__ out) {
    // map flat block id -> (degree d, tile t)
    int cnts[6];
    #pragma unroll
    for (int dd = 0; dd < 6; dd++) cnts[dd] = gcnt[dd];
    const int bid = blockIdx.x;
    int d = -1, t = 0, accum = 0;
    #pragma unroll
    for (int dd = 0; dd < 6; dd++) {
        int tl = (cnts[dd] + 127) >> 7;
        if (d < 0 && bid < accum + tl) { d = dd; t = bid - accum; }
        accum += tl;
    }
    if (d < 0) return;
    const int count = cnts[d];
    const int m0 = t * 128;
    const int nrows = min(128, count - m0);

    __shared__ __attribute__((aligned(16))) ushort_t Bsh[128 * 136];
    __shared__ int ids[128];

    const int tid = threadIdx.x;
    if (tid < 128) {
        int idx = m0 + tid;
        if (idx >= count) idx = count - 1;     // clamp; stores masked by nrows
        ids[tid] = region[d * BN + idx];
    }
    // stage W[d] bf16 [n][k] -> LDS pad 136
    {
        const uint4* Wg = (const uint4*)(Wt + (size_t)d * 16384);
        #pragma unroll
        for (int i = 0; i < 8; i++) {
            int idx = tid + i * 256;           // uint4 chunks, 2048 total
            int n = idx >> 4, c = idx & 15;
            *(uint4*)&Bsh[n * 136 + c * 8] = Wg[idx];
        }
    }
    __syncthreads();

    const int lane = tid & 63, w = tid >> 6;
    const int arow0 = w * 32;                  // this wave's 32 atoms
    const int kq = lane >> 4;                  // 0..3
    const int ml = lane & 15;

    // summed-frags from global (used as B operand: B[k][n=atom])
    bf16x8 af[2][4];
    #pragma unroll
    for (int mt = 0; mt < 2; mt++) {
        const int row = ids[arow0 + mt * 16 + ml];
        const bf16x8* sp = (const bf16x8*)(summed + (size_t)row * Ff + kq * 8);
        #pragma unroll
        for (int k0 = 0; k0 < 4; k0++) af[mt][k0] = sp[k0 * 4];   // +32 elts
    }
    const bool v0 = (arow0 + ml) < nrows;      // atom-tile 0 valid (per-lane)
    const bool v1 = (arow0 + 16 + ml) < nrows;
    const int o0 = v0 ? (int)((size_t)ids[arow0 + ml] * Ff) : 0;
    const int o1 = v1 ? (int)((size_t)ids[arow0 + 16 + ml] * Ff) : 0;

    #pragma unroll
    for (int nt = 0; nt < 8; nt++) {           // out-col tiles
        bf16x8 wfr[4];
        #pragma unroll
        for (int k0 = 0; k0 < 4; k0++)
            wfr[k0] = *(const bf16x8*)&Bsh[(nt * 16 + ml) * 136 + k0 * 32 + kq * 8];
        f32x4 c0 = {0.f, 0.f, 0.f, 0.f}, c1 = {0.f, 0.f, 0.f, 0.f};
        #pragma unroll
        for (int k0 = 0; k0 < 4; k0++) {
            // D = W_frag(A) * summed_frag(B): D[m=outcol][n=atom]
            c0 = __builtin_amdgcn_mfma_f32_16x16x32_bf16(wfr[k0], af[0][k0], c0, 0, 0, 0);
            c1 = __builtin_amdgcn_mfma_f32_16x16x32_bf16(wfr[k0], af[1][k0], c1, 0, 0, 0);
        }
        // lane holds outcols nt*16+kq*4..+3 for atom ml (tile 0) / 16+ml (tile 1)
        const int colb = nt * 16 + kq * 4;
        const float4 bv = *(const float4*)&bias[d * Ff + colb];
        float4 r0, r1;
        r0.x = fmaxf(c0[0] + bv.x, 0.f); r0.y = fmaxf(c0[1] + bv.y, 0.f);
        r0.z = fmaxf(c0[2] + bv.z, 0.f); r0.w = fmaxf(c0[3] + bv.w, 0.f);
        r1.x = fmaxf(c1[0] + bv.x, 0.f); r1.y = fmaxf(c1[1] + bv.y, 0.f);
        r1.z = fmaxf(c1[2] + bv.z, 0.f); r1.w = fmaxf(c1[3] + bv.w, 0.f);
        if (v0) *(float4*)&out[o0 + colb] = r0;
        if (v1) *(float4*)&out[o1 + colb] = r1;
    }
}

// ---------------- fallback (round-1 kernel) if ws too small ----------------
__global__ __launch_bounds__(128, 2)
void graphconv_fallback(const float* __restrict__ atoms,
                        const int* __restrict__ edges_raw,
                        const float* __restrict__ W,
                        const float* __restrict__ bias,
                        float* __restrict__ out) {
    const int tid = threadIdx.x;
    const int d = blockIdx.x % 6;
    const int k = blockIdx.x / 6;
    const int a0 = k * 256;
    __shared__ int eds[256 * 6];
    __shared__ int list[256];
    __shared__ int cnt;
    __shared__ float sv[2][Ff];
    bool is64;
    { int v = edges_raw[2 * (tid & 63) + 1]; is64 = (__ballot(v > 0) == 0ull); }
    if (!is64) { for (int i = tid; i < 256 * 6; i += 128) eds[i] = edges_raw[a0 * 6 + i]; }
    else       { for (int i = tid; i < 256 * 6; i += 128) eds[i] = edges_raw[2 * (a0 * 6 + i)]; }
    if (tid == 0) cnt = 0;
    __syncthreads();
    for (int i = tid; i < 256; i += 128) {
        int deg = 0;
        #pragma unroll
        for (int j = 0; j < 6; j++) deg += (eds[i * 6 + j] != -1) ? 1 : 0;
        if (deg == d) { int p = atomicAdd(&cnt, 1); list[p] = i; }
    }
    float Wreg[Ff];
    { const float* Wd = W + (size_t)d * Ff * Ff;
      #pragma unroll
      for (int f = 0; f < Ff; f++) Wreg[f] = Wd[f * Ff + tid]; }
    const float breg = bias[d * Ff + tid];
    __syncthreads();
    const int n = cnt;
    const float* batch_atoms = atoms + (size_t)(a0 / Nn) * Nn * Ff;
    const int row0 = a0 % Nn;
    for (int ii = 0; ii < n; ii++) {
        const int i = list[ii];
        float s = batch_atoms[(row0 + i) * Ff + tid];
        #pragma unroll
        for (int j = 0; j < 6; j++) {
            int e = eds[i * 6 + j];
            if (e != -1) s += batch_atoms[e * Ff + tid];
        }
        float* buf = sv[ii & 1];
        buf[tid] = s;
        __syncthreads();
        float acc = breg;
        const float4* sv4 = (const float4*)buf;
        #pragma unroll
        for (int fc = 0; fc < Ff / 4; fc++) {
            float4 x = sv4[fc];
            acc = fmaf(x.x, Wreg[4 * fc + 0], acc);
            acc = fmaf(x.y, Wreg[4 * fc + 1], acc);
            acc = fmaf(x.z, Wreg[4 * fc + 2], acc);
            acc = fmaf(x.w, Wreg[4 * fc + 3], acc);
        }
        out[(size_t)(a0 + i) * Ff + tid] = fmaxf(acc, 0.0f);
    }
}

extern "C" void kernel_launch(void* const* d_in, const int* in_sizes, int n_in,
                              void* d_out, int out_size, void* d_ws, size_t ws_size,
                              hipStream_t stream) {
    const float* atoms = (const float*)d_in[0];
    const int*   edges = (const int*)d_in[1];
    const float* W     = (const float*)d_in[2];
    const float* bias  = (const float*)d_in[3];
    float*       outp  = (float*)d_out;

    if (ws_size >= WS_NEEDED) {
        char* ws = (char*)d_ws;
        int*      gcnt   = (int*)(ws + WS_GC);
        int*      region = (int*)(ws + WS_REGION);
        ushort_t* Wt     = (ushort_t*)(ws + WS_WT);
        ushort_t* summed = (ushort_t*)(ws + WS_SUMMED);

        hipMemsetAsync(gcnt, 0, 32, stream);
        k1_pre<<<2048, 256, 0, stream>>>(atoms, edges, W, gcnt, region, Wt, summed);
        k2_gemm<<<1030, 256, 0, stream>>>(summed, bias, Wt, region, gcnt, outp);
    } else {
        graphconv_fallback<<<3072, 128, 0, stream>>>(atoms, edges, W, bias, outp);
    }
}